// Round 1
// baseline (1335.640 us; speedup 1.0000x reference)
//
#include <hip/hip_runtime.h>
#include <cstdint>
#include <cstddef>

#define N_ROWS 131072   // B*T
#define T_LEN 2048
#define B_BATCH 64
#define H_DIM 128
#define GEMM_GRID 1024
#define ROWS_PER_BLOCK (N_ROWS / GEMM_GRID)  // 128
#define GROWS 8

// ---------------------------------------------------------------------------
// Kernel 1: Wx = x @ W^T, fused per-column sum / sum-of-squares for BN stats.
// Thread (h = tid>>1, kh = tid&1) holds W[h][kh*64 .. +63] in 16 float4 regs;
// x rows staged in double-buffered LDS; x reads are LDS broadcasts.
// ---------------------------------------------------------------------------
__global__ __launch_bounds__(256) void gemm_bn_kernel(
    const float* __restrict__ x, const float* __restrict__ W,
    float* __restrict__ Wx, float* __restrict__ stats)
{
  const int tid  = threadIdx.x;
  const int h    = tid >> 1;
  const int koff = (tid & 1) << 6;

  float4 Wr[16];
  {
    const float4* wrow = reinterpret_cast<const float4*>(W + h * H_DIM + koff);
#pragma unroll
    for (int j = 0; j < 16; ++j) Wr[j] = wrow[j];
  }

  __shared__ __align__(16) float xs[2][GROWS][H_DIM];
  const int r0  = blockIdx.x * ROWS_PER_BLOCK;
  const int sr  = tid >> 5;          // staging row 0..7
  const int sc4 = (tid & 31) << 2;   // staging col (float4)

  *reinterpret_cast<float4*>(&xs[0][sr][sc4]) =
      *reinterpret_cast<const float4*>(&x[(size_t)(r0 + sr) * H_DIM + sc4]);
  __syncthreads();

  float sum = 0.f, sq = 0.f;

  for (int rt = 0; rt < ROWS_PER_BLOCK; rt += GROWS) {
    const int nb = (rt >> 3) & 1;
    if (rt + GROWS < ROWS_PER_BLOCK) {
      *reinterpret_cast<float4*>(&xs[nb ^ 1][sr][sc4]) =
          *reinterpret_cast<const float4*>(
              &x[(size_t)(r0 + rt + GROWS + sr) * H_DIM + sc4]);
    }
#pragma unroll
    for (int r = 0; r < GROWS; ++r) {
      const float4* y4 = reinterpret_cast<const float4*>(&xs[nb][r][koff]);
      float acc0 = 0.f, acc1 = 0.f, acc2 = 0.f, acc3 = 0.f;
#pragma unroll
      for (int j = 0; j < 4; ++j) {
        float4 a = y4[j * 4 + 0];
        float4 b = y4[j * 4 + 1];
        float4 c = y4[j * 4 + 2];
        float4 d = y4[j * 4 + 3];
        acc0 = fmaf(a.w, Wr[j*4+0].w, fmaf(a.z, Wr[j*4+0].z, fmaf(a.y, Wr[j*4+0].y, fmaf(a.x, Wr[j*4+0].x, acc0))));
        acc1 = fmaf(b.w, Wr[j*4+1].w, fmaf(b.z, Wr[j*4+1].z, fmaf(b.y, Wr[j*4+1].y, fmaf(b.x, Wr[j*4+1].x, acc1))));
        acc2 = fmaf(c.w, Wr[j*4+2].w, fmaf(c.z, Wr[j*4+2].z, fmaf(c.y, Wr[j*4+2].y, fmaf(c.x, Wr[j*4+2].x, acc2))));
        acc3 = fmaf(d.w, Wr[j*4+3].w, fmaf(d.z, Wr[j*4+3].z, fmaf(d.y, Wr[j*4+3].y, fmaf(d.x, Wr[j*4+3].x, acc3))));
      }
      float dot = (acc0 + acc1) + (acc2 + acc3);
      dot += __shfl_xor(dot, 1);   // combine the two k-halves (same h, adjacent lanes)
      if (tid & 1) {
        Wx[(size_t)(r0 + rt + r) * H_DIM + h] = dot;
      } else {
        sum += dot;
        sq  = fmaf(dot, dot, sq);
      }
    }
    __syncthreads();
  }
  if (!(tid & 1)) {  // exactly one even thread per h per block
    atomicAdd(&stats[h], sum);
    atomicAdd(&stats[H_DIM + h], sq);
  }
}

// ---------------------------------------------------------------------------
// Kernel 2: fold BN stats into scale/shift: norm(v) = v*scale[h] + shift[h]
// ---------------------------------------------------------------------------
__global__ void bn_finalize_kernel(float* ws, const float* __restrict__ gamma,
                                   const float* __restrict__ beta)
{
  const int h = threadIdx.x;
  const float invN = 1.0f / (float)N_ROWS;
  float mean = ws[h] * invN;
  float e2   = ws[H_DIM + h] * invN;
  float var  = e2 - mean * mean;
  float scl  = gamma[h] * rsqrtf(var + 1e-5f);
  ws[2 * H_DIM + h] = scl;
  ws[3 * H_DIM + h] = beta[h] - mean * scl;
}

// ---------------------------------------------------------------------------
// Kernel 3: recurrence y_t = sigmoid(norm(Wx_t) + y_{t-1} @ V^T), in-place on
// d_out (which holds Wx). One block per batch, 1024 threads:
//   thread (h = tid>>3, ks = tid&7) owns V[h][ks*16 .. +15] in 4 float4 regs.
// y ping-pongs in LDS; Wx staged 8 steps/window into LDS (issue-early /
// ds_write-late); per-step sync is raw lgkmcnt(0)+s_barrier so the window's
// global loads and the y-store flush stay in flight across barriers.
// ---------------------------------------------------------------------------
__global__ __launch_bounds__(1024) void rnn_kernel(
    const float* __restrict__ V, float* __restrict__ out,
    const float* __restrict__ ws)
{
  const int tid  = threadIdx.x;
  const int h    = tid >> 3;
  const int ks   = tid & 7;
  const int koff = ks << 4;

  float4 Vr[4];
  {
    const float4* vrow = reinterpret_cast<const float4*>(V + h * H_DIM + koff);
#pragma unroll
    for (int j = 0; j < 4; ++j) Vr[j] = vrow[j];
  }
  const float scl = ws[2 * H_DIM + h];
  const float shf = ws[3 * H_DIM + h];

  __shared__ __align__(16) float ylds[2][H_DIM];
  __shared__ __align__(16) float wxs[2][8 * H_DIM];

  float* outb = out + (size_t)blockIdx.x * T_LEN * H_DIM;

  if (tid < H_DIM) ylds[0][tid] = 0.0f;
  wxs[0][tid] = outb[tid];  // stage steps 0..7
  __syncthreads();

  float yreg[8];

  for (int w = 0; w < T_LEN; w += 8) {
    const int bw = (w >> 3) & 1;
    const bool do_stage = (w + 8 < T_LEN);
    float stage_v = 0.0f;
    if (do_stage) stage_v = outb[(size_t)(w + 8) * H_DIM + tid];  // issued early

#pragma unroll
    for (int u = 0; u < 8; ++u) {
      const int t = w + u;
      const float wx = wxs[bw][(u << 7) + h];
      const float* yb = ylds[t & 1];
      const float4* y4 = reinterpret_cast<const float4*>(yb + koff);
      float4 a0 = y4[0], a1 = y4[1], a2 = y4[2], a3 = y4[3];
      float acc0 = fmaf(a0.w, Vr[0].w, fmaf(a0.z, Vr[0].z, fmaf(a0.y, Vr[0].y, a0.x * Vr[0].x)));
      float acc1 = fmaf(a1.w, Vr[1].w, fmaf(a1.z, Vr[1].z, fmaf(a1.y, Vr[1].y, a1.x * Vr[1].x)));
      float acc2 = fmaf(a2.w, Vr[2].w, fmaf(a2.z, Vr[2].z, fmaf(a2.y, Vr[2].y, a2.x * Vr[2].x)));
      float acc3 = fmaf(a3.w, Vr[3].w, fmaf(a3.z, Vr[3].z, fmaf(a3.y, Vr[3].y, a3.x * Vr[3].x)));
      float dot = (acc0 + acc1) + (acc2 + acc3);
      dot += __shfl_xor(dot, 1);
      dot += __shfl_xor(dot, 2);
      dot += __shfl_xor(dot, 4);
      const float s = fmaf(wx, scl, shf) + dot;
      const float y = __builtin_amdgcn_rcpf(1.0f + __expf(-s));
      if (ks == 0) ylds[(t & 1) ^ 1][h] = y;
      yreg[u] = y;
      // LDS-visibility barrier only; global loads/stores stay in flight.
      asm volatile("s_waitcnt lgkmcnt(0)\n\ts_barrier" ::: "memory");
    }

    if (ks == 1) {  // flush the window's outputs (overwrites consumed Wx)
      const size_t base = (size_t)w * H_DIM + h;
#pragma unroll
      for (int u = 0; u < 8; ++u) outb[base + (size_t)u * H_DIM] = yreg[u];
    }
    if (do_stage) wxs[bw ^ 1][tid] = stage_v;  // compiler inserts counted vmcnt wait here
    asm volatile("s_waitcnt lgkmcnt(0)\n\ts_barrier" ::: "memory");
  }
}

// ---------------------------------------------------------------------------
extern "C" void kernel_launch(void* const* d_in, const int* in_sizes, int n_in,
                              void* d_out, int out_size, void* d_ws, size_t ws_size,
                              hipStream_t stream)
{
  (void)in_sizes; (void)n_in; (void)out_size; (void)ws_size;
  const float* x     = (const float*)d_in[0];
  const float* W     = (const float*)d_in[1];
  const float* V     = (const float*)d_in[2];
  const float* gamma = (const float*)d_in[3];
  const float* beta  = (const float*)d_in[4];
  float* out = (float*)d_out;
  float* ws  = (float*)d_ws;

  // zero BN stat accumulators (ws is poisoned, not re-zeroed by harness)
  hipMemsetAsync(ws, 0, 2 * H_DIM * sizeof(float), stream);
  gemm_bn_kernel<<<GEMM_GRID, 256, 0, stream>>>(x, W, out, ws);
  bn_finalize_kernel<<<1, H_DIM, 0, stream>>>(ws, gamma, beta);
  rnn_kernel<<<B_BATCH, 1024, 0, stream>>>(V, out, ws);
}

// Round 2
// 928.926 us; speedup vs baseline: 1.4378x; 1.4378x over previous
//
#include <hip/hip_runtime.h>
#include <cstdint>
#include <cstddef>

#define N_ROWS 131072   // B*T
#define T_LEN 2048
#define B_BATCH 64
#define H_DIM 128
#define GEMM_GRID 1024
#define GEMM_ROWS 128   // rows per gemm block
#define WND 8

// 128-float vector stored as 8 slices of 16 floats, slice stride 20 floats
// (80 B): slice bases hit banks {0,20,8,28,16,4,24,12} -> conflict-free
// ds_read_b128 when the 8 ks-slices are read concurrently.
#define VEC_SWZ 160
#define SWZ(k) ((((k) >> 4) * 20) + ((k) & 15))

__device__ __forceinline__ float sigmoid_fast(float s) {
  return __builtin_amdgcn_rcpf(1.0f + __expf(-s));
}

// p = dot(16-float slice a0..a3, WR[0..3]) as 4 independent FMA chains
#define DOT16(P, WR)                                                          \
  {                                                                           \
    float c0 = fmaf(a0.w, WR[0].w, fmaf(a0.z, WR[0].z, fmaf(a0.y, WR[0].y, a0.x * WR[0].x))); \
    float c1 = fmaf(a1.w, WR[1].w, fmaf(a1.z, WR[1].z, fmaf(a1.y, WR[1].y, a1.x * WR[1].x))); \
    float c2 = fmaf(a2.w, WR[2].w, fmaf(a2.z, WR[2].z, fmaf(a2.y, WR[2].y, a2.x * WR[2].x))); \
    float c3 = fmaf(a3.w, WR[3].w, fmaf(a3.z, WR[3].z, fmaf(a3.y, WR[3].y, a3.x * WR[3].x))); \
    P = (c0 + c1) + (c2 + c3);                                                \
  }

// reduce-scatter over the 8 ks lanes: p0..p3 (rows hq+32r) -> s = full dot of
// row h_own = hq + 32*m_own, m_own = ((ks&1)<<1)|((ks>>1)&1). 4 shfl total.
#define REDUCE_SCATTER(S, p0, p1, p2, p3, ks)                                 \
  float S;                                                                    \
  {                                                                           \
    float x1 = ((ks) & 1) ? p0 : p2;                                          \
    float x2 = ((ks) & 1) ? p1 : p3;                                          \
    float q0 = (((ks) & 1) ? p2 : p0) + __shfl_xor(x1, 1);                    \
    float q1 = (((ks) & 1) ? p3 : p1) + __shfl_xor(x2, 1);                    \
    float x3 = ((ks) & 2) ? q0 : q1;                                          \
    float s1 = (((ks) & 2) ? q1 : q0) + __shfl_xor(x3, 2);                    \
    S = s1 + __shfl_xor(s1, 4);                                               \
  }

// ---------------------------------------------------------------------------
// Kernel 1: Wx = x @ W^T + fused BN column stats.
// 256 thr: lane (hq,ks) holds W rows {hq+32r} x k-slice [16ks,16ks+16) in
// regs; x rows staged (double-buffered, swizzled) in LDS, broadcast-read.
// ---------------------------------------------------------------------------
__global__ __launch_bounds__(256) void gemm_bn_kernel(
    const float* __restrict__ x, const float* __restrict__ W,
    float* __restrict__ Wx, float* __restrict__ stats)
{
  const int tid = threadIdx.x;
  const int hq = tid >> 3;   // 0..31
  const int ks = tid & 7;    // 0..7
  const int k0 = ks << 4;
  const int m_own = ((ks & 1) << 1) | ((ks >> 1) & 1);
  const int h_own = hq + (m_own << 5);

  float4 Wr[4][4];
#pragma unroll
  for (int r = 0; r < 4; ++r) {
    const float4* wp = reinterpret_cast<const float4*>(W + (size_t)(hq + (r << 5)) * H_DIM + k0);
#pragma unroll
    for (int j = 0; j < 4; ++j) Wr[r][j] = wp[j];
  }

  __shared__ __align__(16) float xs[2][WND * VEC_SWZ];

  const int r0 = blockIdx.x * GEMM_ROWS;
  const int sr = tid >> 5;   // staging row 0..7
  const int c4 = tid & 31;   // staging float4 col
  const int sdst = sr * VEC_SWZ + (c4 >> 2) * 20 + (c4 & 3) * 4;

  *reinterpret_cast<float4*>(&xs[0][sdst]) =
      *reinterpret_cast<const float4*>(&x[(size_t)(r0 + sr) * H_DIM + (c4 << 2)]);
  __syncthreads();

  float sum = 0.f, sq = 0.f;

  for (int wnd = 0; wnd < GEMM_ROWS; wnd += WND) {
    const int bw = (wnd >> 3) & 1;
    const bool more = (wnd + WND < GEMM_ROWS);
    float4 sv;
    if (more)
      sv = *reinterpret_cast<const float4*>(
          &x[(size_t)(r0 + wnd + WND + sr) * H_DIM + (c4 << 2)]);

#pragma unroll
    for (int r = 0; r < WND; ++r) {
      const float4* xv = reinterpret_cast<const float4*>(&xs[bw][r * VEC_SWZ + ks * 20]);
      float4 a0 = xv[0], a1 = xv[1], a2 = xv[2], a3 = xv[3];
      float p0, p1, p2, p3;
      DOT16(p0, Wr[0]); DOT16(p1, Wr[1]); DOT16(p2, Wr[2]); DOT16(p3, Wr[3]);
      REDUCE_SCATTER(s, p0, p1, p2, p3, ks);
      if (ks < 4) {
        Wx[(size_t)(r0 + wnd + r) * H_DIM + h_own] = s;
        sum += s;
        sq = fmaf(s, s, sq);
      }
    }
    if (more) *reinterpret_cast<float4*>(&xs[bw ^ 1][sdst]) = sv;
    __syncthreads();
  }
  if (ks < 4) {
    atomicAdd(&stats[h_own], sum);
    atomicAdd(&stats[H_DIM + h_own], sq);
  }
}

// ---------------------------------------------------------------------------
// Kernel 2: fold BN stats into scale/shift
// ---------------------------------------------------------------------------
__global__ void bn_finalize_kernel(float* ws, const float* __restrict__ gamma,
                                   const float* __restrict__ beta)
{
  const int h = threadIdx.x;
  const float invN = 1.0f / (float)N_ROWS;
  float mean = ws[h] * invN;
  float e2   = ws[H_DIM + h] * invN;
  float var  = e2 - mean * mean;
  float scl  = gamma[h] * rsqrtf(var + 1e-5f);
  ws[2 * H_DIM + h] = scl;
  ws[3 * H_DIM + h] = beta[h] - mean * scl;
}

// ---------------------------------------------------------------------------
// Kernel 3: recurrence, in-place on d_out (holds Wx). One block/batch,
// 256 thr (4 waves). Lane (hq,ks): V rows {hq+32r} x 16-float k-slice in
// regs; y ping-pong in swizzled LDS; wx prefetched per 8-step window into
// regs straight from global (no LDS staging); raw 4-wave barrier per step.
// ---------------------------------------------------------------------------
__global__ __launch_bounds__(256) void rnn_kernel(
    const float* __restrict__ V, float* __restrict__ out,
    const float* __restrict__ ws)
{
  const int tid = threadIdx.x;
  const int hq = tid >> 3;
  const int ks = tid & 7;
  const int k0 = ks << 4;
  const int m_own = ((ks & 1) << 1) | ((ks >> 1) & 1);
  const int h_own = hq + (m_own << 5);

  float4 Vr[4][4];
#pragma unroll
  for (int r = 0; r < 4; ++r) {
    const float4* vp = reinterpret_cast<const float4*>(V + (size_t)(hq + (r << 5)) * H_DIM + k0);
#pragma unroll
    for (int j = 0; j < 4; ++j) Vr[r][j] = vp[j];
  }
  const float scl = ws[2 * H_DIM + h_own];
  const float shf = ws[3 * H_DIM + h_own];

  __shared__ __align__(16) float ylds[2][VEC_SWZ];

  float* outb = out + (size_t)blockIdx.x * T_LEN * H_DIM;
  const int swz_own = SWZ(h_own);

  if (tid < VEC_SWZ) ylds[0][tid] = 0.0f;

  float wxp[WND];
#pragma unroll
  for (int u = 0; u < WND; ++u) wxp[u] = outb[(size_t)u * H_DIM + h_own];
  __syncthreads();

  float yreg[WND];

  for (int w = 0; w < T_LEN; w += WND) {
    const bool more = (w + WND < T_LEN);
    float wxn[WND];
    if (more) {  // prefetch next window's wx (latency hides under 8 steps)
#pragma unroll
      for (int u = 0; u < WND; ++u)
        wxn[u] = outb[(size_t)(w + WND + u) * H_DIM + h_own];
    }

#pragma unroll
    for (int u = 0; u < WND; ++u) {
      const int t = w + u;
      const float4* yv = reinterpret_cast<const float4*>(&ylds[t & 1][ks * 20]);
      float4 a0 = yv[0], a1 = yv[1], a2 = yv[2], a3 = yv[3];
      float p0, p1, p2, p3;
      DOT16(p0, Vr[0]); DOT16(p1, Vr[1]); DOT16(p2, Vr[2]); DOT16(p3, Vr[3]);
      REDUCE_SCATTER(dot, p0, p1, p2, p3, ks);
      const float y = sigmoid_fast(fmaf(wxp[u], scl, shf) + dot);
      if (ks < 4) ylds[(t & 1) ^ 1][swz_own] = y;
      yreg[u] = y;
      // LDS visibility only; global loads/stores stay in flight.
      asm volatile("s_waitcnt lgkmcnt(0)\n\ts_barrier" ::: "memory");
    }

    if (ks < 4) {  // flush window outputs (overwrites consumed Wx)
#pragma unroll
      for (int u = 0; u < WND; ++u)
        outb[(size_t)(w + u) * H_DIM + h_own] = yreg[u];
    }
    if (more) {
#pragma unroll
      for (int u = 0; u < WND; ++u) wxp[u] = wxn[u];
    }
  }
}

// ---------------------------------------------------------------------------
extern "C" void kernel_launch(void* const* d_in, const int* in_sizes, int n_in,
                              void* d_out, int out_size, void* d_ws, size_t ws_size,
                              hipStream_t stream)
{
  (void)in_sizes; (void)n_in; (void)out_size; (void)ws_size;
  const float* x     = (const float*)d_in[0];
  const float* W     = (const float*)d_in[1];
  const float* V     = (const float*)d_in[2];
  const float* gamma = (const float*)d_in[3];
  const float* beta  = (const float*)d_in[4];
  float* out = (float*)d_out;
  float* ws  = (float*)d_ws;

  hipMemsetAsync(ws, 0, 2 * H_DIM * sizeof(float), stream);
  gemm_bn_kernel<<<GEMM_GRID, 256, 0, stream>>>(x, W, out, ws);
  bn_finalize_kernel<<<1, H_DIM, 0, stream>>>(ws, gamma, beta);
  rnn_kernel<<<B_BATCH, 256, 0, stream>>>(V, out, ws);
}

// Round 3
// 696.036 us; speedup vs baseline: 1.9189x; 1.3346x over previous
//
#include <hip/hip_runtime.h>
#include <cstdint>
#include <cstddef>

#define N_ROWS 131072   // B*T
#define T_LEN 2048
#define B_BATCH 64
#define H_DIM 128
#define GEMM_GRID 1024
#define GEMM_ROWS 128   // rows per gemm block
#define WND 8

// 128-float vector stored as 8 slices of 16 floats, slice stride 20 floats
// (80 B): slice bases hit banks {0,20,8,28,16,4,24,12} -> conflict-free.
#define VEC_SWZ 160
#define SWZ(k) ((((k) >> 4) * 20) + ((k) & 15))

__device__ __forceinline__ float sigmoid_fast(float s) {
  return __builtin_amdgcn_rcpf(1.0f + __expf(-s));
}

// DPP quad_perm cross-lane xor (VALU, no LDS pipe):
// xor1 = quad_perm(1,0,3,2) = 0xB1 ; xor2 = quad_perm(2,3,0,1) = 0x4E
__device__ __forceinline__ float dpp_xor1(float x) {
  int i = __float_as_int(x);
  return __int_as_float(__builtin_amdgcn_update_dpp(i, i, 0xB1, 0xF, 0xF, true));
}
__device__ __forceinline__ float dpp_xor2(float x) {
  int i = __float_as_int(x);
  return __int_as_float(__builtin_amdgcn_update_dpp(i, i, 0x4E, 0xF, 0xF, true));
}

__device__ __forceinline__ float dot4(float4 a, float4 b, float acc) {
  return fmaf(a.w, b.w, fmaf(a.z, b.z, fmaf(a.y, b.y, fmaf(a.x, b.x, acc))));
}

// p = dot(32-float slice a0..a7, VR[0..7]) : 4 chains of 8 fma + tree
#define DOT32(P, VR)                                                          \
  {                                                                           \
    float c0 = dot4(a4, VR[4], dot4(a0, VR[0], 0.f));                         \
    float c1 = dot4(a5, VR[5], dot4(a1, VR[1], 0.f));                         \
    float c2 = dot4(a6, VR[6], dot4(a2, VR[2], 0.f));                         \
    float c3 = dot4(a7, VR[7], dot4(a3, VR[3], 0.f));                         \
    P = (c0 + c1) + (c2 + c3);                                                \
  }

// Lane (hq = tid>>2, ks = tid&3) owns k-slice [32ks, 32ks+32) of rows
// {hq, hq+64}; row order parity-swapped so the butterfly needs no selects.
// After: S = full dot of row h_own = hq + 64*(ks&1). Writers: ks<2.
#define REDUCE2(S, p0, p1)                                                    \
  float S;                                                                    \
  {                                                                           \
    float q = p0 + dpp_xor1(p1);                                              \
    S = q + dpp_xor2(q);                                                      \
  }

// ---------------------------------------------------------------------------
// Kernel 1: Wx = x @ W^T + fused BN column stats.
// ---------------------------------------------------------------------------
__global__ __launch_bounds__(256) void gemm_bn_kernel(
    const float* __restrict__ x, const float* __restrict__ W,
    float* __restrict__ Wx, float* __restrict__ stats)
{
  const int tid = threadIdx.x;
  const int hq = tid >> 2;           // 0..63
  const int ks = tid & 3;            // 0..3
  const int k0 = ks << 5;            // 32-float k-slice base
  const int h_own = hq + ((ks & 1) << 6);
  const int h_alt = hq + (((ks & 1) ^ 1) << 6);

  float4 Wr[2][8];
  {
    const float4* w0 = reinterpret_cast<const float4*>(W + (size_t)h_own * H_DIM + k0);
    const float4* w1 = reinterpret_cast<const float4*>(W + (size_t)h_alt * H_DIM + k0);
#pragma unroll
    for (int j = 0; j < 8; ++j) { Wr[0][j] = w0[j]; Wr[1][j] = w1[j]; }
  }

  __shared__ __align__(16) float xs[2][WND * VEC_SWZ];

  const int r0 = blockIdx.x * GEMM_ROWS;
  const int sr = tid >> 5;   // staging row 0..7
  const int c4 = tid & 31;   // staging float4 col
  const int sdst = sr * VEC_SWZ + (c4 >> 2) * 20 + (c4 & 3) * 4;

  *reinterpret_cast<float4*>(&xs[0][sdst]) =
      *reinterpret_cast<const float4*>(&x[(size_t)(r0 + sr) * H_DIM + (c4 << 2)]);
  __syncthreads();

  float sum = 0.f, sq = 0.f;

  for (int wnd = 0; wnd < GEMM_ROWS; wnd += WND) {
    const int bw = (wnd >> 3) & 1;
    const bool more = (wnd + WND < GEMM_ROWS);
    float4 sv;
    if (more)
      sv = *reinterpret_cast<const float4*>(
          &x[(size_t)(r0 + wnd + WND + sr) * H_DIM + (c4 << 2)]);

#pragma unroll
    for (int r = 0; r < WND; ++r) {
      const float* xp = &xs[bw][r * VEC_SWZ + ks * 40];
      const float4* xa = reinterpret_cast<const float4*>(xp);
      const float4* xb = reinterpret_cast<const float4*>(xp + 20);
      float4 a0 = xa[0], a1 = xa[1], a2 = xa[2], a3 = xa[3];
      float4 a4 = xb[0], a5 = xb[1], a6 = xb[2], a7 = xb[3];
      float p0, p1;
      DOT32(p0, Wr[0]); DOT32(p1, Wr[1]);
      REDUCE2(s, p0, p1);
      if (ks < 2) {
        Wx[(size_t)(r0 + wnd + r) * H_DIM + h_own] = s;
        sum += s;
        sq = fmaf(s, s, sq);
      }
    }
    if (more) *reinterpret_cast<float4*>(&xs[bw ^ 1][sdst]) = sv;
    __syncthreads();
  }
  if (ks < 2) {
    atomicAdd(&stats[h_own], sum);
    atomicAdd(&stats[H_DIM + h_own], sq);
  }
}

// ---------------------------------------------------------------------------
// Kernel 2: fold BN stats into scale/shift
// ---------------------------------------------------------------------------
__global__ void bn_finalize_kernel(float* ws, const float* __restrict__ gamma,
                                   const float* __restrict__ beta)
{
  const int h = threadIdx.x;
  const float invN = 1.0f / (float)N_ROWS;
  float mean = ws[h] * invN;
  float e2   = ws[H_DIM + h] * invN;
  float var  = e2 - mean * mean;
  float scl  = gamma[h] * rsqrtf(var + 1e-5f);
  ws[2 * H_DIM + h] = scl;
  ws[3 * H_DIM + h] = beta[h] - mean * scl;
}

// ---------------------------------------------------------------------------
// Kernel 3: recurrence, in-place on d_out (holds Wx). One block/batch,
// 256 thr (4 waves). Pure-DPP reduce; y ping-pong in swizzled LDS; wx
// prefetched per 8-step window straight into regs; raw 4-wave barrier.
// ---------------------------------------------------------------------------
__global__ __launch_bounds__(256) void rnn_kernel(
    const float* __restrict__ V, float* __restrict__ out,
    const float* __restrict__ ws)
{
  const int tid = threadIdx.x;
  const int hq = tid >> 2;
  const int ks = tid & 3;
  const int k0 = ks << 5;
  const int h_own = hq + ((ks & 1) << 6);
  const int h_alt = hq + (((ks & 1) ^ 1) << 6);

  float4 Vr[2][8];
  {
    const float4* v0 = reinterpret_cast<const float4*>(V + (size_t)h_own * H_DIM + k0);
    const float4* v1 = reinterpret_cast<const float4*>(V + (size_t)h_alt * H_DIM + k0);
#pragma unroll
    for (int j = 0; j < 8; ++j) { Vr[0][j] = v0[j]; Vr[1][j] = v1[j]; }
  }
  const float scl = ws[2 * H_DIM + h_own];
  const float shf = ws[3 * H_DIM + h_own];

  __shared__ __align__(16) float ylds[2][VEC_SWZ];

  float* outb = out + (size_t)blockIdx.x * T_LEN * H_DIM;
  const int swz_own = SWZ(h_own);

  if (tid < VEC_SWZ) { ylds[0][tid] = 0.0f; ylds[1][tid] = 0.0f; }

  float wxp[WND];
#pragma unroll
  for (int u = 0; u < WND; ++u) wxp[u] = outb[(size_t)u * H_DIM + h_own];
  __syncthreads();

  float yreg[WND];

  for (int w = 0; w < T_LEN; w += WND) {
    const bool more = (w + WND < T_LEN);
    float wxn[WND];
    if (more) {  // prefetch next window's wx (latency hides under 8 steps)
#pragma unroll
      for (int u = 0; u < WND; ++u)
        wxn[u] = outb[(size_t)(w + WND + u) * H_DIM + h_own];
    }

#pragma unroll
    for (int u = 0; u < WND; ++u) {
      const int t = w + u;
      const float* yp = &ylds[t & 1][ks * 40];
      const float4* ya = reinterpret_cast<const float4*>(yp);
      const float4* yb = reinterpret_cast<const float4*>(yp + 20);
      float4 a0 = ya[0], a1 = ya[1], a2 = ya[2], a3 = ya[3];
      float4 a4 = yb[0], a5 = yb[1], a6 = yb[2], a7 = yb[3];
      float p0, p1;
      DOT32(p0, Vr[0]); DOT32(p1, Vr[1]);
      REDUCE2(dot, p0, p1);
      const float y = sigmoid_fast(fmaf(wxp[u], scl, shf) + dot);
      if (ks < 2) ylds[(t & 1) ^ 1][swz_own] = y;
      yreg[u] = y;
      // LDS visibility only; global loads/stores stay in flight.
      asm volatile("s_waitcnt lgkmcnt(0)\n\ts_barrier" ::: "memory");
    }

    if (ks < 2) {  // flush window outputs (overwrites consumed Wx)
#pragma unroll
      for (int u = 0; u < WND; ++u)
        outb[(size_t)(w + u) * H_DIM + h_own] = yreg[u];
    }
    if (more) {
#pragma unroll
      for (int u = 0; u < WND; ++u) wxp[u] = wxn[u];
    }
  }
}

// ---------------------------------------------------------------------------
extern "C" void kernel_launch(void* const* d_in, const int* in_sizes, int n_in,
                              void* d_out, int out_size, void* d_ws, size_t ws_size,
                              hipStream_t stream)
{
  (void)in_sizes; (void)n_in; (void)out_size; (void)ws_size;
  const float* x     = (const float*)d_in[0];
  const float* W     = (const float*)d_in[1];
  const float* V     = (const float*)d_in[2];
  const float* gamma = (const float*)d_in[3];
  const float* beta  = (const float*)d_in[4];
  float* out = (float*)d_out;
  float* ws  = (float*)d_ws;

  hipMemsetAsync(ws, 0, 2 * H_DIM * sizeof(float), stream);
  gemm_bn_kernel<<<GEMM_GRID, 256, 0, stream>>>(x, W, out, ws);
  bn_finalize_kernel<<<1, H_DIM, 0, stream>>>(ws, gamma, beta);
  rnn_kernel<<<B_BATCH, 256, 0, stream>>>(V, out, ws);
}

// Round 4
// 539.520 us; speedup vs baseline: 2.4756x; 1.2901x over previous
//
#include <hip/hip_runtime.h>
#include <cstdint>
#include <cstddef>

#define N_ROWS 131072   // B*T
#define T_LEN 2048
#define B_BATCH 64
#define H_DIM 128
#define GEMM_GRID 1024
#define GEMM_ROWS 128   // rows per gemm block
#define WND 8
#define LOG2E 1.4426950408889634f

// 128-float vector stored as 8 slices of 16 floats, slice stride 20 floats
// (80 B): slice bases hit banks {0,20,8,28,16,4,24,12} -> conflict-free.
// (used by the GEMM staging only)
#define VEC_SWZ 160

typedef _Float16 half2_t __attribute__((ext_vector_type(2)));

// DPP cross-lane ops (VALU pipe, no LDS):
// quad_perm(1,0,3,2)=0xB1 (xor1), quad_perm(2,3,0,1)=0x4E (xor2),
// ROW_HALF_MIRROR=0x141 (l <-> l^7 within each 8-lane group).
__device__ __forceinline__ float dpp_xor1(float x) {
  int i = __float_as_int(x);
  return __int_as_float(__builtin_amdgcn_update_dpp(i, i, 0xB1, 0xF, 0xF, true));
}
__device__ __forceinline__ float dpp_xor2(float x) {
  int i = __float_as_int(x);
  return __int_as_float(__builtin_amdgcn_update_dpp(i, i, 0x4E, 0xF, 0xF, true));
}
__device__ __forceinline__ float dpp_mirror8(float x) {
  int i = __float_as_int(x);
  return __int_as_float(__builtin_amdgcn_update_dpp(i, i, 0x141, 0xF, 0xF, true));
}

__device__ __forceinline__ float dot4(float4 a, float4 b, float acc) {
  return fmaf(a.w, b.w, fmaf(a.z, b.z, fmaf(a.y, b.y, fmaf(a.x, b.x, acc))));
}

// ========================= GEMM (unchanged from R2) =========================
#define DOT32(P, VR)                                                          \
  {                                                                           \
    float c0 = dot4(a4, VR[4], dot4(a0, VR[0], 0.f));                         \
    float c1 = dot4(a5, VR[5], dot4(a1, VR[1], 0.f));                         \
    float c2 = dot4(a6, VR[6], dot4(a2, VR[2], 0.f));                         \
    float c3 = dot4(a7, VR[7], dot4(a3, VR[3], 0.f));                         \
    P = (c0 + c1) + (c2 + c3);                                                \
  }
#define REDUCE2(S, p0, p1)                                                    \
  float S;                                                                    \
  {                                                                           \
    float q = p0 + dpp_xor1(p1);                                              \
    S = q + dpp_xor2(q);                                                      \
  }

__global__ __launch_bounds__(256) void gemm_bn_kernel(
    const float* __restrict__ x, const float* __restrict__ W,
    float* __restrict__ Wx, float* __restrict__ stats)
{
  const int tid = threadIdx.x;
  const int hq = tid >> 2;           // 0..63
  const int ks = tid & 3;            // 0..3
  const int k0 = ks << 5;            // 32-float k-slice base
  const int h_own = hq + ((ks & 1) << 6);
  const int h_alt = hq + (((ks & 1) ^ 1) << 6);

  float4 Wr[2][8];
  {
    const float4* w0 = reinterpret_cast<const float4*>(W + (size_t)h_own * H_DIM + k0);
    const float4* w1 = reinterpret_cast<const float4*>(W + (size_t)h_alt * H_DIM + k0);
#pragma unroll
    for (int j = 0; j < 8; ++j) { Wr[0][j] = w0[j]; Wr[1][j] = w1[j]; }
  }

  __shared__ __align__(16) float xs[2][WND * VEC_SWZ];

  const int r0 = blockIdx.x * GEMM_ROWS;
  const int sr = tid >> 5;   // staging row 0..7
  const int c4 = tid & 31;   // staging float4 col
  const int sdst = sr * VEC_SWZ + (c4 >> 2) * 20 + (c4 & 3) * 4;

  *reinterpret_cast<float4*>(&xs[0][sdst]) =
      *reinterpret_cast<const float4*>(&x[(size_t)(r0 + sr) * H_DIM + (c4 << 2)]);
  __syncthreads();

  float sum = 0.f, sq = 0.f;

  for (int wnd = 0; wnd < GEMM_ROWS; wnd += WND) {
    const int bw = (wnd >> 3) & 1;
    const bool more = (wnd + WND < GEMM_ROWS);
    float4 sv;
    if (more)
      sv = *reinterpret_cast<const float4*>(
          &x[(size_t)(r0 + wnd + WND + sr) * H_DIM + (c4 << 2)]);

#pragma unroll
    for (int r = 0; r < WND; ++r) {
      const float* xp = &xs[bw][r * VEC_SWZ + ks * 40];
      const float4* xa = reinterpret_cast<const float4*>(xp);
      const float4* xb = reinterpret_cast<const float4*>(xp + 20);
      float4 a0 = xa[0], a1 = xa[1], a2 = xa[2], a3 = xa[3];
      float4 a4 = xb[0], a5 = xb[1], a6 = xb[2], a7 = xb[3];
      float p0, p1;
      DOT32(p0, Wr[0]); DOT32(p1, Wr[1]);
      REDUCE2(s, p0, p1);
      if (ks < 2) {
        Wx[(size_t)(r0 + wnd + r) * H_DIM + h_own] = s;
        sum += s;
        sq = fmaf(s, s, sq);
      }
    }
    if (more) *reinterpret_cast<float4*>(&xs[bw ^ 1][sdst]) = sv;
    __syncthreads();
  }
  if (ks < 2) {
    atomicAdd(&stats[h_own], sum);
    atomicAdd(&stats[H_DIM + h_own], sq);
  }
}

// ---------------------------------------------------------------------------
__global__ void bn_finalize_kernel(float* ws, const float* __restrict__ gamma,
                                   const float* __restrict__ beta)
{
  const int h = threadIdx.x;
  const float invN = 1.0f / (float)N_ROWS;
  float mean = ws[h] * invN;
  float e2   = ws[H_DIM + h] * invN;
  float var  = e2 - mean * mean;
  float scl  = gamma[h] * rsqrtf(var + 1e-5f);
  ws[2 * H_DIM + h] = scl;
  ws[3 * H_DIM + h] = beta[h] - mean * scl;
}

// ---------------------------------------------------------------------------
// Kernel 3: recurrence, in-place on d_out (holds Wx). One block/batch,
// 256 thr (4 waves). f16 y in LDS ping-pong; V as f16 pre-scaled by -log2e
// (exp2-domain sigmoid); per-lane: 4 rows x 16-k slice via v_dot2_f32_f16;
// select-free 3-stage DPP reduce-scatter (xor1, xor2, row_half_mirror).
// Lane l (within 8-group): accumulator j holds row j ^ g, g=(l&3)^(3*(l>>2&1)).
// ---------------------------------------------------------------------------
__global__ __launch_bounds__(256) void rnn_kernel(
    const float* __restrict__ V, float* __restrict__ out,
    const float* __restrict__ ws)
{
  const int tid = threadIdx.x;
  const int hq = tid >> 3;           // 0..31
  const int l7 = tid & 7;            // lane within 8-group
  const int g  = (l7 & 3) ^ (3 * ((l7 >> 2) & 1));
  const int h_own = hq + (g << 5);
  const bool wr = (tid & 4) == 0;    // lanes l7<4: unique row owners/writers

  // V fragment: rows h_j = hq + 32*(j^g), k-slice [16*l7, 16*l7+16), as f16
  // pre-scaled by -log2e.
  half2_t Vh[4][8];
#pragma unroll
  for (int j = 0; j < 4; ++j) {
    const int hrow = hq + (((unsigned)(j ^ g)) << 5);
    const float* vp = V + (size_t)hrow * H_DIM + (l7 << 4);
#pragma unroll
    for (int i = 0; i < 8; ++i) {
      half2_t h;
      h.x = (_Float16)(-LOG2E * vp[2 * i]);
      h.y = (_Float16)(-LOG2E * vp[2 * i + 1]);
      Vh[j][i] = h;
    }
  }
  const float scl2 = ws[2 * H_DIM + h_own] * (-LOG2E);
  const float shf2 = ws[3 * H_DIM + h_own] * (-LOG2E);

  __shared__ __align__(16) _Float16 ylds[2][H_DIM];

  float* outb = out + (size_t)blockIdx.x * T_LEN * H_DIM;

  if (tid < H_DIM) { ylds[0][tid] = (_Float16)0.f; ylds[1][tid] = (_Float16)0.f; }

  float wxp[WND];
  if (wr) {
#pragma unroll
    for (int u = 0; u < WND; ++u)
      wxp[u] = fmaf(outb[(size_t)u * H_DIM + h_own], scl2, shf2);
  } else {
#pragma unroll
    for (int u = 0; u < WND; ++u) wxp[u] = 0.f;
  }
  __syncthreads();

  float yreg[WND];

  for (int w = 0; w < T_LEN; w += WND) {
    const bool more = (w + WND < T_LEN);
    float wxn[WND];
    if (more && wr) {  // prefetch next window's wx (hides under 8 steps)
#pragma unroll
      for (int u = 0; u < WND; ++u)
        wxn[u] = outb[(size_t)(w + WND + u) * H_DIM + h_own];
    } else {
#pragma unroll
      for (int u = 0; u < WND; ++u) wxn[u] = 0.f;
    }

#pragma unroll
    for (int u = 0; u < WND; ++u) {
      const int t = w + u;
      // read own 16-half slice of y (2 x ds_read_b128, mostly broadcast)
      const uint4* yv = reinterpret_cast<const uint4*>(&ylds[t & 1][l7 << 4]);
      uint4 w0 = yv[0], w1 = yv[1];
      half2_t y2[8];
      y2[0] = __builtin_bit_cast(half2_t, w0.x);
      y2[1] = __builtin_bit_cast(half2_t, w0.y);
      y2[2] = __builtin_bit_cast(half2_t, w0.z);
      y2[3] = __builtin_bit_cast(half2_t, w0.w);
      y2[4] = __builtin_bit_cast(half2_t, w1.x);
      y2[5] = __builtin_bit_cast(half2_t, w1.y);
      y2[6] = __builtin_bit_cast(half2_t, w1.z);
      y2[7] = __builtin_bit_cast(half2_t, w1.w);

      float a0 = 0.f, a1 = 0.f, a2 = 0.f, a3 = 0.f;
#pragma unroll
      for (int i = 0; i < 8; ++i) {
        a0 = __builtin_amdgcn_fdot2(y2[i], Vh[0][i], a0, false);
        a1 = __builtin_amdgcn_fdot2(y2[i], Vh[1][i], a1, false);
        a2 = __builtin_amdgcn_fdot2(y2[i], Vh[2][i], a2, false);
        a3 = __builtin_amdgcn_fdot2(y2[i], Vh[3][i], a3, false);
      }
      // select-free reduce-scatter: lane ends with full dot of row g
      float b0 = a0 + dpp_xor1(a1);
      float b1 = a2 + dpp_xor1(a3);
      float c  = b0 + dpp_xor2(b1);
      float red = c + dpp_mirror8(c);
      // s'' = -log2e * (wx*scl + shf + dot)  -> y = 1/(1+2^{s''})
      const float spp = red + wxp[u];
      const float y = __builtin_amdgcn_rcpf(1.0f + __builtin_amdgcn_exp2f(spp));
      if (wr) ylds[(t & 1) ^ 1][h_own] = (_Float16)y;
      yreg[u] = y;
      // LDS visibility only; global loads/stores stay in flight.
      asm volatile("s_waitcnt lgkmcnt(0)\n\ts_barrier" ::: "memory");
    }

    if (wr) {  // flush window outputs (overwrites consumed Wx)
#pragma unroll
      for (int u = 0; u < WND; ++u)
        outb[(size_t)(w + u) * H_DIM + h_own] = yreg[u];
    }
#pragma unroll
    for (int u = 0; u < WND; ++u) wxp[u] = fmaf(wxn[u], scl2, shf2);
  }
}

// ---------------------------------------------------------------------------
extern "C" void kernel_launch(void* const* d_in, const int* in_sizes, int n_in,
                              void* d_out, int out_size, void* d_ws, size_t ws_size,
                              hipStream_t stream)
{
  (void)in_sizes; (void)n_in; (void)out_size; (void)ws_size;
  const float* x     = (const float*)d_in[0];
  const float* W     = (const float*)d_in[1];
  const float* V     = (const float*)d_in[2];
  const float* gamma = (const float*)d_in[3];
  const float* beta  = (const float*)d_in[4];
  float* out = (float*)d_out;
  float* ws  = (float*)d_ws;

  hipMemsetAsync(ws, 0, 2 * H_DIM * sizeof(float), stream);
  gemm_bn_kernel<<<GEMM_GRID, 256, 0, stream>>>(x, W, out, ws);
  bn_finalize_kernel<<<1, H_DIM, 0, stream>>>(ws, gamma, beta);
  rnn_kernel<<<B_BATCH, 256, 0, stream>>>(V, out, ws);
}